// Round 3
// 193.148 us; speedup vs baseline: 1.0692x; 1.0692x over previous
//
#include <hip/hip_runtime.h>

typedef __bf16 bf16x8 __attribute__((ext_vector_type(8)));
typedef float f32x4 __attribute__((ext_vector_type(4)));

#define HW 9216
#define ZSTR 176      // padded row stride (40 | 96 | 40)
#define ZSLAB 16896   // 96*176 elems per (sl,ch,img) slab
#define XTILE 32768   // shorts per xb/Wsb tile: 32 chunks x 128 rows x 8 elems

__device__ __forceinline__ unsigned short f2bf(float f) {
  unsigned u = __float_as_uint(f);
  unsigned r = (u + 0x7FFFu + ((u >> 16) & 1u)) >> 16;
  return (unsigned short)r;
}
__device__ __forceinline__ float bf2f(unsigned short h) {
  return __uint_as_float(((unsigned)h) << 16);
}

__device__ __forceinline__ void async16(const unsigned short* g, unsigned short* l) {
  __builtin_amdgcn_global_load_lds(
      (const __attribute__((address_space(1))) unsigned int*)g,
      (__attribute__((address_space(3))) unsigned int*)l, 16, 0, 0);
}

// y[j] += w[j] * z[O+j], z drawn from the 16-elem window {lo,hi}, O compile-time
template <int O>
__device__ __forceinline__ void tapfma(float* y, uint4 lo, uint4 hi, uint4 wv) {
  const unsigned short* lu = (const unsigned short*)&lo;
  const unsigned short* hu = (const unsigned short*)&hi;
  const unsigned short* wu = (const unsigned short*)&wv;
#pragma unroll
  for (int j = 0; j < 8; ++j) {
    unsigned short zz = (O + j < 8) ? lu[O + j] : hu[O + j - 8];
    y[j] += bf2f(wu[j]) * bf2f(zz);
  }
}

// one 9-tap branch; dy-invalid taps: address clamped to valid row, weight zeroed
template <int B, int D>
__device__ __forceinline__ void branch9(float* y, const unsigned short* zslab,
                                        const unsigned short* gb, int h, int w0) {
#define TAPK(K, DY, DX)                                                       \
  {                                                                           \
    int hh = h + (DY);                                                        \
    int hc = min(max(hh, 0), 95);                                             \
    const unsigned short* zr = zslab + hc * ZSTR;                             \
    constexpr int O = (40 + (DX)) & 7;                                        \
    int eb = 40 + w0 + (DX)-O;                                                \
    uint4 lo = *(const uint4*)(zr + eb);                                      \
    uint4 hi = *(const uint4*)(zr + eb + 8);                                  \
    uint4 wv = *(const uint4*)(gb + (size_t)(((B - 1) * 9 + (K)) * 2) * HW);  \
    if ((unsigned)hh >= 96u) wv = make_uint4(0u, 0u, 0u, 0u);                 \
    tapfma<O>(y, lo, hi, wv);                                                 \
  }
  TAPK(0, -D, -D) TAPK(1, -D, 0) TAPK(2, -D, D)
  TAPK(3, 0, -D)  TAPK(4, 0, 0)  TAPK(5, 0, D)
  TAPK(6, D, -D)  TAPK(7, D, 0)  TAPK(8, D, D)
#undef TAPK
}

// ---------- init (merged): xpose->tiled | weight repack (tiled Wsb) | zero z pads
// xb tiled: [144 tiles(128 rows)][32 chunks(8 k)][128 rows][8] shorts
__global__ __launch_bounds__(256) void init_all(const float* __restrict__ x,
                                                const float* __restrict__ Ws,
                                                const float* __restrict__ Wc,
                                                unsigned short* __restrict__ xb,
                                                unsigned short* __restrict__ Wsb,
                                                unsigned short* __restrict__ Wcb,
                                                unsigned short* __restrict__ z) {
  __shared__ float tile[64][65];
  int id = blockIdx.x;
  int t = threadIdx.x;
  if (id < 1152) {  // xpose
    int bx = id % 144, by = (id / 144) % 4, n = id / 576;
    int p0 = bx * 64, ci0 = by * 64;
    int cl = t & 63, q = t >> 6;
#pragma unroll
    for (int i = 0; i < 16; ++i) {
      int cir = q + i * 4;
      tile[cir][cl] = x[((size_t)(n * 256 + ci0 + cir)) * HW + p0 + cl];
    }
    __syncthreads();
    // write: lane = row, 2 uint4 (=2 chunks of 8 ch) per thread, contiguous
    int R = n * HW + p0 + cl;
    int Rt = R >> 7, Rl = R & 127;
#pragma unroll
    for (int i = 0; i < 2; ++i) {
      int cloc = q * 2 + i;  // chunk-local 0..7
      unsigned rr[4];
#pragma unroll
      for (int jj = 0; jj < 4; ++jj) {
        unsigned short a = f2bf(tile[cloc * 8 + jj * 2][cl]);
        unsigned short b = f2bf(tile[cloc * 8 + jj * 2 + 1][cl]);
        rr[jj] = (unsigned)a | ((unsigned)b << 16);
      }
      *(uint4*)(xb + (size_t)Rt * XTILE + (by * 8 + cloc) * 1024 + Rl * 8) =
          make_uint4(rr[0], rr[1], rr[2], rr[3]);
    }
  } else if (id < 3120) {  // weight repack
    int u = (id - 1152) * 256 + t;
    if (u < 393216) {  // Wsb tiled: [12 tiles][32 chunks][128 rows][8]
      int r = u >> 8, k = u & 255;
      Wsb[(size_t)(r >> 7) * XTILE + (k >> 3) * 1024 + (r & 127) * 8 + (k & 7)] =
          f2bf(Ws[(size_t)(r & 255) * 1536 + (r >> 8) * 256 + k]);
    } else {
      int v = u - 393216;
      if (v < 110592) {
        int co = v / 2304, rr = v % 2304;
        int j = rr >> 8, ci = rr & 255;
        Wcb[v] = (co < 45) ? f2bf(Wc[(size_t)co * 2304 + ci * 9 + j]) : (unsigned short)0;
      }
    }
  } else {  // zero pads
    int r = (id - 3120) * 256 + t;
    unsigned short* base = z + (size_t)r * ZSTR;
    uint4 zero = make_uint4(0u, 0u, 0u, 0u);
#pragma unroll
    for (int i = 0; i < 5; ++i) *(uint4*)(base + i * 8) = zero;
#pragma unroll
    for (int i = 0; i < 5; ++i) *(uint4*)(base + 136 + i * 8) = zero;
  }
}

// ---------- gemms: gemm_g first (288 blocks) | gemm_z (contiguous DMA) ----------
__global__ __launch_bounds__(256) void gemms(const unsigned short* __restrict__ xb,
                                             const unsigned short* __restrict__ Wsb,
                                             const unsigned short* __restrict__ Wcb,
                                             unsigned short* __restrict__ z,
                                             unsigned short* __restrict__ gsmb) {
  __shared__ unsigned short smem[16384];  // 32KB
  int id = blockIdx.x;
  int t = threadIdx.x;
  int wid = t >> 6, lane = t & 63;
  int q = lane >> 4, ln = lane & 15;

  if (id < 288) {
    // ===== gemm_g: BM=64 BN=48 BK=64 (36 steps), reg-prefetch, fused softmax =====
    unsigned short* As = smem;          // 8 kq x 64 mm x uint4 = 8KB
    unsigned short* Bs = smem + 4096;   // 8 kq x 48 nn x uint4 = 6KB
    int m0 = id * 64;
    int mm = t >> 2, kq = t & 3;
    int m = m0 + mm;
    int img = m / HW, p = m % HW;
    int h = p / 96, w = p % 96;
    int mbase = img * HW;
    int nn = t >> 2;  // for Bs (t<192)
    f32x4 acc[3] = {};
    uint4 aA0, aA1, aB0, aB1;

    // prefetch step 0 (tap j=0 -> dy=-1,dx=-1; chunks kq, kq+4 of tile)
    {
      int hh = h - 1, ww = w - 1;
      bool valid = ((unsigned)hh < 96u) & ((unsigned)ww < 96u);
      int R = mbase + hh * 96 + ww;
      const unsigned short* pa =
          xb + (long)(R >> 7) * XTILE + kq * 1024 + (R & 127) * 8;
      aA0 = valid ? *(const uint4*)pa : make_uint4(0, 0, 0, 0);
      aA1 = valid ? *(const uint4*)(pa + 4096) : make_uint4(0, 0, 0, 0);
      if (t < 192) {
        const unsigned short* pb = Wcb + (size_t)nn * 2304 + kq * 8;
        aB0 = *(const uint4*)pb;
        aB1 = *(const uint4*)(pb + 32);
      }
    }

    for (int s = 0; s < 36; ++s) {
      ((uint4*)As)[kq * 64 + mm] = aA0;
      ((uint4*)As)[(kq + 4) * 64 + mm] = aA1;
      if (t < 192) {
        ((uint4*)Bs)[kq * 48 + nn] = aB0;
        ((uint4*)Bs)[(kq + 4) * 48 + nn] = aB1;
      }
      __syncthreads();
      if (s + 1 < 36) {  // prefetch next step; consumed next iteration
        int s1 = s + 1;
        int j = s1 >> 2;
        int hh = h + j / 3 - 1, ww = w + j % 3 - 1;
        bool valid = ((unsigned)hh < 96u) & ((unsigned)ww < 96u);
        int R = mbase + hh * 96 + ww;
        const unsigned short* pa = xb + (long)(R >> 7) * XTILE +
                                   ((s1 & 3) * 8 + kq) * 1024 + (R & 127) * 8;
        aA0 = valid ? *(const uint4*)pa : make_uint4(0, 0, 0, 0);
        aA1 = valid ? *(const uint4*)(pa + 4096) : make_uint4(0, 0, 0, 0);
        if (t < 192) {
          const unsigned short* pb = Wcb + (size_t)nn * 2304 + s1 * 64 + kq * 8;
          aB0 = *(const uint4*)pb;
          aB1 = *(const uint4*)(pb + 32);
        }
      }
#pragma unroll
      for (int kk = 0; kk < 2; ++kk) {
        bf16x8 a = ((const bf16x8*)As)[(kk * 4 + q) * 64 + wid * 16 + ln];
#pragma unroll
        for (int fn = 0; fn < 3; ++fn) {
          bf16x8 b = ((const bf16x8*)Bs)[(kk * 4 + q) * 48 + fn * 16 + ln];
          acc[fn] = __builtin_amdgcn_mfma_f32_16x16x32_bf16(a, b, acc[fn], 0, 0, 0);
        }
      }
      __syncthreads();
    }

    // fused softmax epilogue: acc -> LDS f32 [64px][49], then 64 threads softmax
    float* LDSf = (float*)smem;  // 64*49*4 = 12544B
#pragma unroll
    for (int fn = 0; fn < 3; ++fn)
#pragma unroll
      for (int r = 0; r < 4; ++r)
        LDSf[(wid * 16 + q * 4 + r) * 49 + fn * 16 + ln] = acc[fn][r];
    __syncthreads();
    if (t < 64) {
      const float* row = LDSf + t * 49;
      int mg = m0 + t;
      int img2 = mg / HW, p2 = mg - img2 * HW;
      for (int grp = 0; grp < 5; ++grp) {
        float v[9], mx = -1e30f;
#pragma unroll
        for (int k = 0; k < 9; ++k) { v[k] = row[grp * 9 + k]; mx = fmaxf(mx, v[k]); }
        float sum = 0.f;
#pragma unroll
        for (int k = 0; k < 9; ++k) { v[k] = __expf(v[k] - mx); sum += v[k]; }
        float inv = 1.f / sum;
#pragma unroll
        for (int k = 0; k < 9; ++k) {
          int col = grp * 9 + k;
          gsmb[((size_t)(col * 2 + img2)) * HW + p2] = f2bf(v[k] * inv);
        }
      }
    }
  } else {
    // ===== gemm_z: 128x128, K=256, double-buffered FULLY-CONTIGUOUS DMA =====
    int zid = id - 288;
    int mt = zid % 144, ct = zid / 144;
    int m0 = mt * 128, c0 = ct * 128;
    int wm = (wid >> 1) * 64, wn = (wid & 1) * 64;
    bool isB = wid >= 2;
    // tiled source: per K-step the 8KB stage region is linear
    const unsigned short* gsrc =
        (isB ? Wsb + (size_t)ct * XTILE : xb + (size_t)mt * XTILE) + lane * 8;
    unsigned short* lb = smem + (isB ? 8192 : 0);
    int ow = (wid & 1) * 4;  // op offset: waves {0,2}->0..3, {1,3}->4..7
    f32x4 acc[4][4] = {};

    // stage step 0 into buffer 0
#pragma unroll
    for (int kq = 0; kq < 4; ++kq)
      async16(gsrc + (ow + kq) * 512, lb + (ow + kq) * 512);
    __syncthreads();

    for (int s = 0; s < 8; ++s) {
      int cur = s & 1, nxt = cur ^ 1;
      if (s < 7) {  // issue next-step DMA; drained by end-of-iter barrier
#pragma unroll
        for (int kq = 0; kq < 4; ++kq)
          async16(gsrc + (s + 1) * 4096 + (ow + kq) * 512,
                  lb + nxt * 4096 + (ow + kq) * 512);
      }
      const unsigned short* Asc = smem + cur * 4096;
      const unsigned short* Bsc = smem + 8192 + cur * 4096;
      bf16x8 a[4], b[4];
#pragma unroll
      for (int f = 0; f < 4; ++f) {
        a[f] = ((const bf16x8*)Asc)[q * 128 + wm + f * 16 + ln];
        b[f] = ((const bf16x8*)Bsc)[q * 128 + wn + f * 16 + ln];
      }
#pragma unroll
      for (int fm = 0; fm < 4; ++fm)
#pragma unroll
        for (int fn = 0; fn < 4; ++fn)
          acc[fm][fn] = __builtin_amdgcn_mfma_f32_16x16x32_bf16(a[fm], b[fn], acc[fm][fn], 0, 0, 0);
      __syncthreads();
    }

    // epilogue: CHW-padded z; 4 consecutive w-px -> one 8B store (L2 merges lines)
    int sl = c0 >> 8, cb = c0 & 255;
    int img = m0 / HW;
    int pbase = m0 - img * HW;
#pragma unroll
    for (int fm = 0; fm < 4; ++fm) {
      int p = pbase + wm + fm * 16 + q * 4;
      int hh = p / 96, ww = p % 96;
#pragma unroll
      for (int fn = 0; fn < 4; ++fn) {
        int ch = cb + wn + fn * 16 + ln;
        size_t slab = ((size_t)(sl * 256 + ch) * 2 + img) * ZSLAB;
        unsigned lo = (unsigned)f2bf(acc[fm][fn][0]) | ((unsigned)f2bf(acc[fm][fn][1]) << 16);
        unsigned hi = (unsigned)f2bf(acc[fm][fn][2]) | ((unsigned)f2bf(acc[fm][fn][3]) << 16);
        *(uint2*)(z + slab + hh * ZSTR + 40 + ww) = make_uint2(lo, hi);
      }
    }
  }
}

// ---------- accum: pure streaming in CHW (padded z — round-0 proven) ----------
__global__ __launch_bounds__(384) void accum_chw(const unsigned short* __restrict__ z,
                                                 const unsigned short* __restrict__ gsmb,
                                                 float* __restrict__ yacc,
                                                 float* __restrict__ stats) {
  __shared__ float red[12];
  int t = threadIdx.x;
  int wq = t % 12, hl = t / 12;
  int h = blockIdx.x * 32 + hl;
  int img = blockIdx.y, ch = blockIdx.z;
  int w0 = wq * 8;
  int p0 = h * 96 + w0;
  const unsigned short* gb = gsmb + (size_t)img * HW + p0;

  float y[8] = {0.f, 0.f, 0.f, 0.f, 0.f, 0.f, 0.f, 0.f};
  {
    const unsigned short* zs = z + ((size_t)(ch * 2 + img)) * ZSLAB;
    uint4 v = *(const uint4*)(zs + h * ZSTR + 40 + w0);
    const unsigned short* u = (const unsigned short*)&v;
#pragma unroll
    for (int j = 0; j < 8; ++j) y[j] += bf2f(u[j]);
  }
  size_t chslab = (size_t)(ch * 2 + img) * ZSLAB;
  branch9<1, 1>(y, z + (size_t)(1 * 512) * ZSLAB + chslab, gb, h, w0);
  branch9<2, 6>(y, z + (size_t)(2 * 512) * ZSLAB + chslab, gb, h, w0);
  branch9<3, 12>(y, z + (size_t)(3 * 512) * ZSLAB + chslab, gb, h, w0);
  branch9<4, 24>(y, z + (size_t)(4 * 512) * ZSLAB + chslab, gb, h, w0);
  branch9<5, 36>(y, z + (size_t)(5 * 512) * ZSLAB + chslab, gb, h, w0);

  size_t ybase = ((size_t)(img * 256 + ch)) * HW + p0;
  *(float4*)(yacc + ybase) = make_float4(y[0], y[1], y[2], y[3]);
  *(float4*)(yacc + ybase + 4) = make_float4(y[4], y[5], y[6], y[7]);

  float s1 = 0.f, s2 = 0.f;
#pragma unroll
  for (int j = 0; j < 8; ++j) { s1 += y[j]; s2 += y[j] * y[j]; }
#pragma unroll
  for (int off = 1; off <= 32; off <<= 1) {
    s1 += __shfl_xor(s1, off);
    s2 += __shfl_xor(s2, off);
  }
  int wid = t >> 6, lane = t & 63;
  if (lane == 0) { red[wid] = s1; red[6 + wid] = s2; }
  __syncthreads();
  if (t == 0) {
    float a = red[0] + red[1] + red[2] + red[3] + red[4] + red[5];
    atomicAdd(&stats[ch], a);
  } else if (t == 64) {
    float b = red[6] + red[7] + red[8] + red[9] + red[10] + red[11];
    atomicAdd(&stats[256 + ch], b);
  }
}

// ---------- bn: elementwise on CHW ----------
__global__ __launch_bounds__(256) void bn_apply(const float* __restrict__ yacc,
                                                const float* __restrict__ stats,
                                                const float* __restrict__ gamma,
                                                const float* __restrict__ beta,
                                                float* __restrict__ out) {
  int q = blockIdx.x * 256 + threadIdx.x;
  int ch = (q / 2304) & 255;
  const float inv_cnt = 1.f / 18432.f;
  float mean = stats[ch] * inv_cnt;
  float var = stats[256 + ch] * inv_cnt - mean * mean;
  float sc = rsqrtf(var + 1e-5f) * gamma[ch];
  float sh = beta[ch] - mean * sc;
  float4 v = *(const float4*)(yacc + (size_t)q * 4);
  float4 o = make_float4(v.x * sc + sh, v.y * sc + sh, v.z * sc + sh, v.w * sc + sh);
  *(float4*)(out + (size_t)q * 4) = o;
}

extern "C" void kernel_launch(void* const* d_in, const int* in_sizes, int n_in,
                              void* d_out, int out_size, void* d_ws, size_t ws_size,
                              hipStream_t stream) {
  const float* x = (const float*)d_in[0];
  const float* Wc = (const float*)d_in[1];
  const float* Ws = (const float*)d_in[2];
  const float* gamma = (const float*)d_in[3];
  const float* beta = (const float*)d_in[4];
  float* out = (float*)d_out;

  unsigned short* xb = (unsigned short*)d_ws;   // 4718592 us (tiled)
  unsigned short* Wsb = xb + 4718592;           // 393216 us  (tiled)
  unsigned short* Wcb = Wsb + 393216;           // 110592 us
  unsigned short* gsmb = Wcb + 110592;          // 829440 us   [45col][2img][9216]
  unsigned short* z = gsmb + 829440;            // 51904512 us [6][256][2][96][176]
  float* yacc = (float*)(z + 51904512);         // 4718592 f32 [img][ch][p]
  float* stats = yacc + 4718592;                // 512 f32

  hipMemsetAsync(stats, 0, 512 * sizeof(float), stream);
  init_all<<<4272, 256, 0, stream>>>(x, Ws, Wc, xb, Wsb, Wcb, z);
  gemms<<<2016, 256, 0, stream>>>(xb, Wsb, Wcb, z, gsmb);
  accum_chw<<<dim3(3, 2, 256), 384, 0, stream>>>(z, gsmb, yacc, stats);
  bn_apply<<<4608, 256, 0, stream>>>(yacc, stats, gamma, beta, out);
}

// Round 4
// 171.952 us; speedup vs baseline: 1.2010x; 1.1233x over previous
//
#include <hip/hip_runtime.h>

typedef __bf16 bf16x8 __attribute__((ext_vector_type(8)));
typedef float f32x4 __attribute__((ext_vector_type(4)));

#define HW 9216
#define ZSLAB 9216   // packed 96*96 elems per (sl,ch,img) slab — no pads
#define XTILE 32768  // shorts per xb/Wsb tile: 32 chunks x 128 rows x 8 elems

__device__ __forceinline__ unsigned short f2bf(float f) {
  unsigned u = __float_as_uint(f);
  unsigned r = (u + 0x7FFFu + ((u >> 16) & 1u)) >> 16;
  return (unsigned short)r;
}
__device__ __forceinline__ float bf2f(unsigned short h) {
  return __uint_as_float(((unsigned)h) << 16);
}

__device__ __forceinline__ void async16(const unsigned short* g, unsigned short* l) {
  __builtin_amdgcn_global_load_lds(
      (const __attribute__((address_space(1))) unsigned int*)g,
      (__attribute__((address_space(3))) unsigned int*)l, 16, 0, 0);
}

// y[j] += w[j] * z[O+j], z drawn from the 16-elem window {lo,hi}, O compile-time
template <int O>
__device__ __forceinline__ void tapfma(float* y, uint4 lo, uint4 hi, uint4 wv) {
  const unsigned short* lu = (const unsigned short*)&lo;
  const unsigned short* hu = (const unsigned short*)&hi;
  const unsigned short* wu = (const unsigned short*)&wv;
#pragma unroll
  for (int j = 0; j < 8; ++j) {
    unsigned short zz = (O + j < 8) ? lu[O + j] : hu[O + j - 8];
    y[j] += bf2f(wu[j]) * bf2f(zz);
  }
}

// one 9-tap branch on packed z. dy-invalid: row clamped + weight zeroed.
// dx-invalid: each 8-elem window is all-valid or all-invalid (starts are
// 8-aligned, 96%8==0) -> window zeroed, address clamped in-row.
template <int B, int D>
__device__ __forceinline__ void branch9(float* y, const unsigned short* zslab,
                                        const unsigned short* gb, int h, int w0) {
#define TAPK(K, DY, DX)                                                       \
  {                                                                           \
    int hh = h + (DY);                                                        \
    int hc = min(max(hh, 0), 95);                                             \
    const unsigned short* zr = zslab + hc * 96;                               \
    constexpr int O = (40 + (DX)) & 7;                                        \
    int s_col = w0 + (DX)-O; /* multiple of 8 */                              \
    int scl = min(max(s_col, 0), 88);                                         \
    int sch = min(max(s_col + 8, 0), 88);                                     \
    uint4 lo = *(const uint4*)(zr + scl);                                     \
    uint4 hi = *(const uint4*)(zr + sch);                                     \
    uint4 wv = *(const uint4*)(gb + (size_t)(((B - 1) * 9 + (K)) * 2) * HW);  \
    if ((unsigned)hh >= 96u) wv = make_uint4(0u, 0u, 0u, 0u);                 \
    if ((unsigned)s_col > 88u) lo = make_uint4(0u, 0u, 0u, 0u);               \
    if ((unsigned)(s_col + 8) > 88u) hi = make_uint4(0u, 0u, 0u, 0u);         \
    tapfma<O>(y, lo, hi, wv);                                                 \
  }
  TAPK(0, -D, -D) TAPK(1, -D, 0) TAPK(2, -D, D)
  TAPK(3, 0, -D)  TAPK(4, 0, 0)  TAPK(5, 0, D)
  TAPK(6, D, -D)  TAPK(7, D, 0)  TAPK(8, D, D)
#undef TAPK
}

// ---------- init: xpose into tiled layout | weight repack (tiled Wsb) ----------
// xb tiled: [144 tiles(128 rows)][32 chunks(8 k)][128 rows][8] shorts
__global__ __launch_bounds__(256) void init_all(const float* __restrict__ x,
                                                const float* __restrict__ Ws,
                                                const float* __restrict__ Wc,
                                                unsigned short* __restrict__ xb,
                                                unsigned short* __restrict__ Wsb,
                                                unsigned short* __restrict__ Wcb) {
  __shared__ float tile[64][65];
  int id = blockIdx.x;
  int t = threadIdx.x;
  if (id < 1152) {  // xpose
    int bx = id % 144, by = (id / 144) % 4, n = id / 576;
    int p0 = bx * 64, ci0 = by * 64;
    int cl = t & 63, q = t >> 6;
#pragma unroll
    for (int i = 0; i < 16; ++i) {
      int cir = q + i * 4;
      tile[cir][cl] = x[((size_t)(n * 256 + ci0 + cir)) * HW + p0 + cl];
    }
    __syncthreads();
    // write: lane = row, 2 uint4 (=2 chunks of 8 ch) per thread, contiguous
    int R = n * HW + p0 + cl;
    int Rt = R >> 7, Rl = R & 127;
#pragma unroll
    for (int i = 0; i < 2; ++i) {
      int cloc = q * 2 + i;  // chunk-local 0..7
      unsigned rr[4];
#pragma unroll
      for (int jj = 0; jj < 4; ++jj) {
        unsigned short a = f2bf(tile[cloc * 8 + jj * 2][cl]);
        unsigned short b = f2bf(tile[cloc * 8 + jj * 2 + 1][cl]);
        rr[jj] = (unsigned)a | ((unsigned)b << 16);
      }
      *(uint4*)(xb + (size_t)Rt * XTILE + (by * 8 + cloc) * 1024 + Rl * 8) =
          make_uint4(rr[0], rr[1], rr[2], rr[3]);
    }
  } else {  // weight repack
    int u = (id - 1152) * 256 + t;
    if (u < 393216) {  // Wsb tiled: [12 tiles][32 chunks][128 rows][8]
      int r = u >> 8, k = u & 255;
      Wsb[(size_t)(r >> 7) * XTILE + (k >> 3) * 1024 + (r & 127) * 8 + (k & 7)] =
          f2bf(Ws[(size_t)(r & 255) * 1536 + (r >> 8) * 256 + k]);
    } else {
      int v = u - 393216;
      if (v < 110592) {
        int co = v / 2304, rr = v % 2304;
        int j = rr >> 8, ci = rr & 255;
        Wcb[v] = (co < 45) ? f2bf(Wc[(size_t)co * 2304 + ci * 9 + j]) : (unsigned short)0;
      }
    }
  }
}

// ---------- gemms: gemm_g first (288 blocks) | gemm_z (contiguous DMA) ----------
__global__ __launch_bounds__(256) void gemms(const unsigned short* __restrict__ xb,
                                             const unsigned short* __restrict__ Wsb,
                                             const unsigned short* __restrict__ Wcb,
                                             unsigned short* __restrict__ z,
                                             unsigned short* __restrict__ gsmb) {
  __shared__ unsigned short smem[16384];  // 32KB
  int id = blockIdx.x;
  int t = threadIdx.x;
  int wid = t >> 6, lane = t & 63;
  int q = lane >> 4, ln = lane & 15;

  if (id < 288) {
    // ===== gemm_g: BM=64 BN=48 BK=64 (36 steps), reg-prefetch, fused softmax =====
    unsigned short* As = smem;          // 8 kq x 64 mm x uint4 = 8KB
    unsigned short* Bs = smem + 4096;   // 8 kq x 48 nn x uint4 = 6KB
    int m0 = id * 64;
    int mm = t >> 2, kq = t & 3;
    int m = m0 + mm;
    int img = m / HW, p = m % HW;
    int h = p / 96, w = p % 96;
    int mbase = img * HW;
    int nn = t >> 2;  // for Bs (t<192)
    f32x4 acc[3] = {};
    uint4 aA0, aA1, aB0, aB1;

    // prefetch step 0 (tap j=0 -> dy=-1,dx=-1; chunks kq, kq+4 of tile)
    {
      int hh = h - 1, ww = w - 1;
      bool valid = ((unsigned)hh < 96u) & ((unsigned)ww < 96u);
      int R = mbase + hh * 96 + ww;
      const unsigned short* pa =
          xb + (long)(R >> 7) * XTILE + kq * 1024 + (R & 127) * 8;
      aA0 = valid ? *(const uint4*)pa : make_uint4(0, 0, 0, 0);
      aA1 = valid ? *(const uint4*)(pa + 4096) : make_uint4(0, 0, 0, 0);
      if (t < 192) {
        const unsigned short* pb = Wcb + (size_t)nn * 2304 + kq * 8;
        aB0 = *(const uint4*)pb;
        aB1 = *(const uint4*)(pb + 32);
      }
    }

    for (int s = 0; s < 36; ++s) {
      ((uint4*)As)[kq * 64 + mm] = aA0;
      ((uint4*)As)[(kq + 4) * 64 + mm] = aA1;
      if (t < 192) {
        ((uint4*)Bs)[kq * 48 + nn] = aB0;
        ((uint4*)Bs)[(kq + 4) * 48 + nn] = aB1;
      }
      __syncthreads();
      if (s + 1 < 36) {  // prefetch next step; consumed next iteration
        int s1 = s + 1;
        int j = s1 >> 2;
        int hh = h + j / 3 - 1, ww = w + j % 3 - 1;
        bool valid = ((unsigned)hh < 96u) & ((unsigned)ww < 96u);
        int R = mbase + hh * 96 + ww;
        const unsigned short* pa = xb + (long)(R >> 7) * XTILE +
                                   ((s1 & 3) * 8 + kq) * 1024 + (R & 127) * 8;
        aA0 = valid ? *(const uint4*)pa : make_uint4(0, 0, 0, 0);
        aA1 = valid ? *(const uint4*)(pa + 4096) : make_uint4(0, 0, 0, 0);
        if (t < 192) {
          const unsigned short* pb = Wcb + (size_t)nn * 2304 + s1 * 64 + kq * 8;
          aB0 = *(const uint4*)pb;
          aB1 = *(const uint4*)(pb + 32);
        }
      }
#pragma unroll
      for (int kk = 0; kk < 2; ++kk) {
        bf16x8 a = ((const bf16x8*)As)[(kk * 4 + q) * 64 + wid * 16 + ln];
#pragma unroll
        for (int fn = 0; fn < 3; ++fn) {
          bf16x8 b = ((const bf16x8*)Bs)[(kk * 4 + q) * 48 + fn * 16 + ln];
          acc[fn] = __builtin_amdgcn_mfma_f32_16x16x32_bf16(a, b, acc[fn], 0, 0, 0);
        }
      }
      __syncthreads();
    }

    // fused softmax epilogue: acc -> LDS f32 [64px][49], then 64 threads softmax
    float* LDSf = (float*)smem;  // 64*49*4 = 12544B
#pragma unroll
    for (int fn = 0; fn < 3; ++fn)
#pragma unroll
      for (int r = 0; r < 4; ++r)
        LDSf[(wid * 16 + q * 4 + r) * 49 + fn * 16 + ln] = acc[fn][r];
    __syncthreads();
    if (t < 64) {
      const float* row = LDSf + t * 49;
      int mg = m0 + t;
      int img2 = mg / HW, p2 = mg - img2 * HW;
      for (int grp = 0; grp < 5; ++grp) {
        float v[9], mx = -1e30f;
#pragma unroll
        for (int k = 0; k < 9; ++k) { v[k] = row[grp * 9 + k]; mx = fmaxf(mx, v[k]); }
        float sum = 0.f;
#pragma unroll
        for (int k = 0; k < 9; ++k) { v[k] = __expf(v[k] - mx); sum += v[k]; }
        float inv = 1.f / sum;
#pragma unroll
        for (int k = 0; k < 9; ++k) {
          int col = grp * 9 + k;
          gsmb[((size_t)(col * 2 + img2)) * HW + p2] = f2bf(v[k] * inv);
        }
      }
    }
  } else {
    // ===== gemm_z: 128x128, K=256, double-buffered FULLY-CONTIGUOUS DMA =====
    int zid = id - 288;
    int mt = zid % 144, ct = zid / 144;
    int m0 = mt * 128, c0 = ct * 128;
    int wm = (wid >> 1) * 64, wn = (wid & 1) * 64;
    bool isB = wid >= 2;
    // tiled source: per K-step the 8KB stage region is linear
    const unsigned short* gsrc =
        (isB ? Wsb + (size_t)ct * XTILE : xb + (size_t)mt * XTILE) + lane * 8;
    unsigned short* lb = smem + (isB ? 8192 : 0);
    int ow = (wid & 1) * 4;  // op offset: waves {0,2}->0..3, {1,3}->4..7
    f32x4 acc[4][4] = {};

    // stage step 0 into buffer 0
#pragma unroll
    for (int kq = 0; kq < 4; ++kq)
      async16(gsrc + (ow + kq) * 512, lb + (ow + kq) * 512);
    __syncthreads();

    for (int s = 0; s < 8; ++s) {
      int cur = s & 1, nxt = cur ^ 1;
      if (s < 7) {  // issue next-step DMA; drained by end-of-iter barrier
#pragma unroll
        for (int kq = 0; kq < 4; ++kq)
          async16(gsrc + (s + 1) * 4096 + (ow + kq) * 512,
                  lb + nxt * 4096 + (ow + kq) * 512);
      }
      const unsigned short* Asc = smem + cur * 4096;
      const unsigned short* Bsc = smem + 8192 + cur * 4096;
      bf16x8 a[4], b[4];
#pragma unroll
      for (int f = 0; f < 4; ++f) {
        a[f] = ((const bf16x8*)Asc)[q * 128 + wm + f * 16 + ln];
        b[f] = ((const bf16x8*)Bsc)[q * 128 + wn + f * 16 + ln];
      }
#pragma unroll
      for (int fm = 0; fm < 4; ++fm)
#pragma unroll
        for (int fn = 0; fn < 4; ++fn)
          acc[fm][fn] = __builtin_amdgcn_mfma_f32_16x16x32_bf16(a[fm], b[fn], acc[fm][fn], 0, 0, 0);
      __syncthreads();
    }

    // epilogue: packed z; per-channel 256B contiguous line-aligned runs
    int sl = c0 >> 8, cb = c0 & 255;
    int img = m0 / HW;
    int pbase = m0 - img * HW;
#pragma unroll
    for (int fm = 0; fm < 4; ++fm) {
      int p = pbase + wm + fm * 16 + q * 4;
#pragma unroll
      for (int fn = 0; fn < 4; ++fn) {
        int ch = cb + wn + fn * 16 + ln;
        size_t slab = ((size_t)(sl * 256 + ch) * 2 + img) * ZSLAB;
        unsigned lo = (unsigned)f2bf(acc[fm][fn][0]) | ((unsigned)f2bf(acc[fm][fn][1]) << 16);
        unsigned hi = (unsigned)f2bf(acc[fm][fn][2]) | ((unsigned)f2bf(acc[fm][fn][3]) << 16);
        *(uint2*)(z + slab + p) = make_uint2(lo, hi);
      }
    }
  }
}

// ---------- accum: pure streaming in CHW (packed z, window masking) ----------
__global__ __launch_bounds__(384) void accum_chw(const unsigned short* __restrict__ z,
                                                 const unsigned short* __restrict__ gsmb,
                                                 float* __restrict__ yacc,
                                                 float* __restrict__ stats) {
  __shared__ float red[12];
  int t = threadIdx.x;
  int wq = t % 12, hl = t / 12;
  int h = blockIdx.x * 32 + hl;
  int img = blockIdx.y, ch = blockIdx.z;
  int w0 = wq * 8;
  int p0 = h * 96 + w0;
  const unsigned short* gb = gsmb + (size_t)img * HW + p0;

  float y[8] = {0.f, 0.f, 0.f, 0.f, 0.f, 0.f, 0.f, 0.f};
  {
    const unsigned short* zs = z + ((size_t)(ch * 2 + img)) * ZSLAB;
    uint4 v = *(const uint4*)(zs + p0);
    const unsigned short* u = (const unsigned short*)&v;
#pragma unroll
    for (int j = 0; j < 8; ++j) y[j] += bf2f(u[j]);
  }
  size_t chslab = (size_t)(ch * 2 + img) * ZSLAB;
  branch9<1, 1>(y, z + (size_t)(1 * 512) * ZSLAB + chslab, gb, h, w0);
  branch9<2, 6>(y, z + (size_t)(2 * 512) * ZSLAB + chslab, gb, h, w0);
  branch9<3, 12>(y, z + (size_t)(3 * 512) * ZSLAB + chslab, gb, h, w0);
  branch9<4, 24>(y, z + (size_t)(4 * 512) * ZSLAB + chslab, gb, h, w0);
  branch9<5, 36>(y, z + (size_t)(5 * 512) * ZSLAB + chslab, gb, h, w0);

  size_t ybase = ((size_t)(img * 256 + ch)) * HW + p0;
  *(float4*)(yacc + ybase) = make_float4(y[0], y[1], y[2], y[3]);
  *(float4*)(yacc + ybase + 4) = make_float4(y[4], y[5], y[6], y[7]);

  float s1 = 0.f, s2 = 0.f;
#pragma unroll
  for (int j = 0; j < 8; ++j) { s1 += y[j]; s2 += y[j] * y[j]; }
#pragma unroll
  for (int off = 1; off <= 32; off <<= 1) {
    s1 += __shfl_xor(s1, off);
    s2 += __shfl_xor(s2, off);
  }
  int wid = t >> 6, lane = t & 63;
  if (lane == 0) { red[wid] = s1; red[6 + wid] = s2; }
  __syncthreads();
  if (t == 0) {
    float a = red[0] + red[1] + red[2] + red[3] + red[4] + red[5];
    atomicAdd(&stats[ch], a);
  } else if (t == 64) {
    float b = red[6] + red[7] + red[8] + red[9] + red[10] + red[11];
    atomicAdd(&stats[256 + ch], b);
  }
}

// ---------- bn: elementwise on CHW ----------
__global__ __launch_bounds__(256) void bn_apply(const float* __restrict__ yacc,
                                                const float* __restrict__ stats,
                                                const float* __restrict__ gamma,
                                                const float* __restrict__ beta,
                                                float* __restrict__ out) {
  int q = blockIdx.x * 256 + threadIdx.x;
  int ch = (q / 2304) & 255;
  const float inv_cnt = 1.f / 18432.f;
  float mean = stats[ch] * inv_cnt;
  float var = stats[256 + ch] * inv_cnt - mean * mean;
  float sc = rsqrtf(var + 1e-5f) * gamma[ch];
  float sh = beta[ch] - mean * sc;
  float4 v = *(const float4*)(yacc + (size_t)q * 4);
  float4 o = make_float4(v.x * sc + sh, v.y * sc + sh, v.z * sc + sh, v.w * sc + sh);
  *(float4*)(out + (size_t)q * 4) = o;
}

extern "C" void kernel_launch(void* const* d_in, const int* in_sizes, int n_in,
                              void* d_out, int out_size, void* d_ws, size_t ws_size,
                              hipStream_t stream) {
  const float* x = (const float*)d_in[0];
  const float* Wc = (const float*)d_in[1];
  const float* Ws = (const float*)d_in[2];
  const float* gamma = (const float*)d_in[3];
  const float* beta = (const float*)d_in[4];
  float* out = (float*)d_out;

  unsigned short* xb = (unsigned short*)d_ws;   // 4718592 us (tiled)
  unsigned short* Wsb = xb + 4718592;           // 393216 us  (tiled)
  unsigned short* Wcb = Wsb + 393216;           // 110592 us
  unsigned short* gsmb = Wcb + 110592;          // 829440 us   [45col][2img][9216]
  unsigned short* z = gsmb + 829440;            // 28311552 us [6][256][2][9216] packed
  float* yacc = (float*)(z + 28311552);         // 4718592 f32 [img][ch][p]
  float* stats = yacc + 4718592;                // 512 f32

  hipMemsetAsync(stats, 0, 512 * sizeof(float), stream);
  init_all<<<3120, 256, 0, stream>>>(x, Ws, Wc, xb, Wsb, Wcb);
  gemms<<<2016, 256, 0, stream>>>(xb, Wsb, Wcb, z, gsmb);
  accum_chw<<<dim3(3, 2, 256), 384, 0, stream>>>(z, gsmb, yacc, stats);
  bn_apply<<<4608, 256, 0, stream>>>(yacc, stats, gamma, beta, out);
}